// Round 5
// baseline (930.509 us; speedup 1.0000x reference)
//
#include <hip/hip_runtime.h>
#include <math.h>

#define N_NODES 50000
#define E_EDGES 800000
#define E_TOT   850000   // E + N self loops
#define HC 128
#define NHEAD 4
#define LIN 256
#define OUTC 10
#define NG 64
#define NEG_SLOPE 0.2f

__device__ __forceinline__ float lrelu(float v) { return v > 0.f ? v : NEG_SLOPE * v; }

// ---------------------------------------------------------------------------
// GEMM + attention logits: h = x@W (N x128 @ 128x128); alpha_{src,dst}[n,h].
// 4 rows x 16 cols per thread; cols interleaved (c = t*4 + 32u) so each
// ds_read_b128 hits all 32 banks conflict-free.
// ---------------------------------------------------------------------------
__global__ __launch_bounds__(256, 2) void k_gemm_alpha(
    const float* __restrict__ x, const float* __restrict__ W,
    const float* __restrict__ a_s, const float* __restrict__ a_d,
    float* __restrict__ h, float* __restrict__ asrc, float* __restrict__ adst) {
  __shared__ float Ws[HC * HC];  // 64 KB
  int tid = threadIdx.x;
  {
    const float4* Wg = (const float4*)W;
    float4* Wv = (float4*)Ws;
#pragma unroll
    for (int i = 0; i < 16; i++) Wv[tid + i * 256] = Wg[tid + i * 256];
  }
  __syncthreads();
  int rl = tid >> 3, t = tid & 7;
  int base = blockIdx.x * 128;
  int row[4];
  const float4* xr[4];
#pragma unroll
  for (int r = 0; r < 4; r++) {
    row[r] = base + rl + 32 * r;
    int rc = row[r] < N_NODES ? row[r] : N_NODES - 1;  // clamp, store-guarded
    xr[r] = (const float4*)(x + (size_t)rc * HC);
  }
  float acc[4][16];
#pragma unroll
  for (int r = 0; r < 4; r++)
#pragma unroll
    for (int j = 0; j < 16; j++) acc[r][j] = 0.f;

  for (int k4 = 0; k4 < 32; k4++) {
    float4 xa = xr[0][k4], xb = xr[1][k4], xc = xr[2][k4], xd = xr[3][k4];
#pragma unroll
    for (int kk = 0; kk < 4; kk++) {
      const float* wb = Ws + (k4 * 4 + kk) * HC + t * 4;
      float4 w0 = *(const float4*)(wb);
      float4 w1 = *(const float4*)(wb + 32);
      float4 w2 = *(const float4*)(wb + 64);
      float4 w3 = *(const float4*)(wb + 96);
      float xs[4];
      xs[0] = (kk == 0) ? xa.x : (kk == 1) ? xa.y : (kk == 2) ? xa.z : xa.w;
      xs[1] = (kk == 0) ? xb.x : (kk == 1) ? xb.y : (kk == 2) ? xb.z : xb.w;
      xs[2] = (kk == 0) ? xc.x : (kk == 1) ? xc.y : (kk == 2) ? xc.z : xc.w;
      xs[3] = (kk == 0) ? xd.x : (kk == 1) ? xd.y : (kk == 2) ? xd.z : xd.w;
#pragma unroll
      for (int r = 0; r < 4; r++) {
        float xv = xs[r];
        acc[r][0] += xv * w0.x;  acc[r][1] += xv * w0.y;
        acc[r][2] += xv * w0.z;  acc[r][3] += xv * w0.w;
        acc[r][4] += xv * w1.x;  acc[r][5] += xv * w1.y;
        acc[r][6] += xv * w1.z;  acc[r][7] += xv * w1.w;
        acc[r][8] += xv * w2.x;  acc[r][9] += xv * w2.y;
        acc[r][10] += xv * w2.z; acc[r][11] += xv * w2.w;
        acc[r][12] += xv * w3.x; acc[r][13] += xv * w3.y;
        acc[r][14] += xv * w3.z; acc[r][15] += xv * w3.w;
      }
    }
  }

#pragma unroll
  for (int r = 0; r < 4; r++) {
    // col c = t*4 + 32u + j  ->  head = u, channel = t*4 + j
    float ps[4], pd[4];
#pragma unroll
    for (int u = 0; u < 4; u++) {
      float s = 0.f, d = 0.f;
#pragma unroll
      for (int j = 0; j < 4; j++) {
        float av = acc[r][u * 4 + j];
        s += av * a_s[u * 32 + t * 4 + j];
        d += av * a_d[u * 32 + t * 4 + j];
      }
      s += __shfl_xor(s, 1); s += __shfl_xor(s, 2); s += __shfl_xor(s, 4);
      d += __shfl_xor(d, 1); d += __shfl_xor(d, 2); d += __shfl_xor(d, 4);
      ps[u] = s; pd[u] = d;
    }
    if (row[r] < N_NODES) {
      float* hr = h + (size_t)row[r] * HC;
#pragma unroll
      for (int u = 0; u < 4; u++)
        *(float4*)(hr + t * 4 + 32 * u) = make_float4(
            acc[r][u * 4 + 0], acc[r][u * 4 + 1], acc[r][u * 4 + 2], acc[r][u * 4 + 3]);
      if (t < 4) {
        float vs = (t == 0) ? ps[0] : (t == 1) ? ps[1] : (t == 2) ? ps[2] : ps[3];
        float vd = (t == 0) ? pd[0] : (t == 1) ? pd[1] : (t == 2) ? pd[2] : pd[3];
        asrc[row[r] * NHEAD + t] = vs;
        adst[row[r] * NHEAD + t] = vd;
      }
    }
  }
}

// ---------------------------------------------------------------------------
// CSR build: histogram -> exclusive scan -> scatter (int atomics only)
// ---------------------------------------------------------------------------
__global__ __launch_bounds__(256) void k_hist(
    const int* __restrict__ dst, int* __restrict__ deg) {
  int e = blockIdx.x * 256 + threadIdx.x;
  if (e >= E_TOT) return;
  int d = (e < E_EDGES) ? dst[e] : e - E_EDGES;
  atomicAdd(&deg[d], 1);
}

__global__ __launch_bounds__(1024) void k_scan(
    const int* __restrict__ deg, int* __restrict__ row_off) {
  __shared__ int ps[1024];
  int tid = threadIdx.x;
  const int CH = (N_NODES + 1023) / 1024;  // 49
  int base = tid * CH;
  int sum = 0;
  for (int i = 0; i < CH; i++) {
    int idx = base + i;
    if (idx < N_NODES) sum += deg[idx];
  }
  ps[tid] = sum;
  __syncthreads();
  for (int off = 1; off < 1024; off <<= 1) {
    int v = (tid >= off) ? ps[tid - off] : 0;
    __syncthreads();
    ps[tid] += v;
    __syncthreads();
  }
  int run = (tid ? ps[tid - 1] : 0);
  for (int i = 0; i < CH; i++) {
    int idx = base + i;
    if (idx < N_NODES) { row_off[idx] = run; run += deg[idx]; }
  }
  if (tid == 1023) row_off[N_NODES] = run;
}

__global__ __launch_bounds__(256) void k_scatter(
    const int* __restrict__ src, const int* __restrict__ dst,
    const int* __restrict__ row_off, int* __restrict__ cnt,
    int* __restrict__ csr_src) {
  int e = blockIdx.x * 256 + threadIdx.x;
  if (e >= E_TOT) return;
  int s, d;
  if (e < E_EDGES) { s = src[e]; d = dst[e]; } else { s = d = e - E_EDGES; }
  int pos = row_off[d] + atomicAdd(&cnt[d], 1);
  csr_src[pos] = s;
}

#define BFLY_MAX4(m0, m1, m2, m3)                         \
  _Pragma("unroll") for (int off = 1; off < 64; off <<= 1) { \
    m0 = fmaxf(m0, __shfl_xor(m0, off));                  \
    m1 = fmaxf(m1, __shfl_xor(m1, off));                  \
    m2 = fmaxf(m2, __shfl_xor(m2, off));                  \
    m3 = fmaxf(m3, __shfl_xor(m3, off));                  \
  }
#define BFLY_SUM4(s0, s1, s2, s3)                         \
  _Pragma("unroll") for (int off = 1; off < 64; off <<= 1) { \
    s0 += __shfl_xor(s0, off);                            \
    s1 += __shfl_xor(s1, off);                            \
    s2 += __shfl_xor(s2, off);                            \
    s3 += __shfl_xor(s3, off);                            \
  }

// ---------------------------------------------------------------------------
// Fused softmax + aggregation. One wave per dst node.
// Stage 1: lane j loads edge j's index + asrc (one batched gather), softmax
//          stats via butterfly shuffles, per-edge weights parked in LDS.
// Stage 2: wave split in halves: lanes 0-31 = even edge, 32-63 = odd edge of
//          each pair; lane owns 4 feats (float4 gather = 2 edge-rows/instr).
//          8-slot rotating prefetch keeps ~16 edges in flight (partial vmcnt).
//          shfl_xor(32) combines halves. Fused bias+relu+(final) max-pool.
// ---------------------------------------------------------------------------
__global__ __launch_bounds__(256) void k_aggr(
    const int* __restrict__ row_off, const int* __restrict__ csr_src,
    const float* __restrict__ asrc, const float* __restrict__ adst,
    const float* __restrict__ h, const float* __restrict__ bias,
    const int* __restrict__ batch, float* __restrict__ out_h,
    unsigned* __restrict__ pooled, int do_pool) {
  __shared__ int   sv_lds[4][64];
  __shared__ float w_lds[4][64][4];
  int gid = blockIdx.x * 256 + threadIdx.x;
  int node = gid >> 6, lane = gid & 63, wl = threadIdx.x >> 6;
  if (node >= N_NODES) return;
  int li = lane & 31, half = lane >> 5, hsel = li >> 3;
  int lo = row_off[node], hi = row_off[node + 1];
  int deg = hi - lo;
  float4 ad4 = ((const float4*)adst)[node];  // broadcast

  if (deg <= 64) {
    // --- stage 1: softmax stats + weights ---
    int j = lo + lane;
    int sv = (j < hi) ? csr_src[j] : 0;
    float4 a4 = ((const float4*)asrc)[sv];
    bool valid = (j < hi);
    float e0 = valid ? lrelu(a4.x + ad4.x) : -1e30f;
    float e1 = valid ? lrelu(a4.y + ad4.y) : -1e30f;
    float e2 = valid ? lrelu(a4.z + ad4.z) : -1e30f;
    float e3 = valid ? lrelu(a4.w + ad4.w) : -1e30f;
    float m0 = e0, m1 = e1, m2 = e2, m3 = e3;
    BFLY_MAX4(m0, m1, m2, m3)
    float w0 = expf(e0 - m0), w1 = expf(e1 - m1);
    float w2 = expf(e2 - m2), w3 = expf(e3 - m3);  // invalid lanes -> 0
    float s0 = w0, s1 = w1, s2 = w2, s3 = w3;
    BFLY_SUM4(s0, s1, s2, s3)
    sv_lds[wl][lane] = sv;
    *(float4*)&w_lds[wl][lane][0] = make_float4(w0, w1, w2, w3);
    float S = (hsel == 0) ? s0 : (hsel == 1) ? s1 : (hsel == 2) ? s2 : s3;
    float rden = 1.f / S;

    // --- stage 2: pipelined float4 gather, 2 edges per instruction ---
    int P = (deg + 1) >> 1;  // pairs
    const int PF = 8;
    float4 hreg[PF];
    float wreg[PF];
#pragma unroll
    for (int s = 0; s < PF; s++) {
      int e = 2 * s + half;
      bool v = (e < deg);
      int ec = v ? e : 0;
      int idx = sv_lds[wl][ec];
      wreg[s] = v ? w_lds[wl][ec][hsel] : 0.f;
      float4 hv = make_float4(0.f, 0.f, 0.f, 0.f);
      if (v) hv = *(const float4*)(h + (size_t)idx * HC + li * 4);
      hreg[s] = hv;
    }
    float4 acc = make_float4(0.f, 0.f, 0.f, 0.f);
    for (int pb = 0; pb < P; pb += PF) {
#pragma unroll
      for (int s = 0; s < PF; s++) {
        float w = wreg[s];
        float4 hv = hreg[s];
        acc.x += w * hv.x; acc.y += w * hv.y;
        acc.z += w * hv.z; acc.w += w * hv.w;
        int pn = pb + s + PF;
        int e = 2 * pn + half;
        bool v = (e < deg);
        int ec = v ? e : 0;
        int idx = sv_lds[wl][ec];
        wreg[s] = v ? w_lds[wl][ec][hsel] : 0.f;
        float4 h2 = make_float4(0.f, 0.f, 0.f, 0.f);
        if (v) h2 = *(const float4*)(h + (size_t)idx * HC + li * 4);
        hreg[s] = h2;
      }
    }
    // combine halves
    acc.x += __shfl_xor(acc.x, 32);
    acc.y += __shfl_xor(acc.y, 32);
    acc.z += __shfl_xor(acc.z, 32);
    acc.w += __shfl_xor(acc.w, 32);
    float4 b4 = ((const float4*)bias)[li];
    float vx = fmaxf(acc.x * rden + b4.x, 0.f);
    float vy = fmaxf(acc.y * rden + b4.y, 0.f);
    float vz = fmaxf(acc.z * rden + b4.z, 0.f);
    float vw = fmaxf(acc.w * rden + b4.w, 0.f);
    if (half == 0) {
      ((float4*)(out_h + (size_t)node * HC))[li] = make_float4(vx, vy, vz, vw);
      if (do_pool) {
        int g = batch[node];
        unsigned* pp = pooled + g * HC + li * 4;
        // post-relu values >= 0: bit compare == float compare; init 0 matches
        // the reference's where(isfinite, pooled, 0) empty-graph guard.
        atomicMax(pp + 0, __float_as_uint(vx));
        atomicMax(pp + 1, __float_as_uint(vy));
        atomicMax(pp + 2, __float_as_uint(vz));
        atomicMax(pp + 3, __float_as_uint(vw));
      }
    }
    return;
  }

  // --- rare generic path (deg > 64): chunked two-pass, float2 layout ---
  int head = lane >> 4;
  float ax = 0.f, ay = 0.f;
  float M0 = -1e30f, M1 = -1e30f, M2 = -1e30f, M3 = -1e30f;
  for (int c = lo; c < hi; c += 64) {
    int j = c + lane;
    int sv = (j < hi) ? csr_src[j] : 0;
    float4 a4 = ((const float4*)asrc)[sv];
    bool valid = (j < hi);
    float e0 = valid ? lrelu(a4.x + ad4.x) : -1e30f;
    float e1 = valid ? lrelu(a4.y + ad4.y) : -1e30f;
    float e2 = valid ? lrelu(a4.z + ad4.z) : -1e30f;
    float e3 = valid ? lrelu(a4.w + ad4.w) : -1e30f;
    BFLY_MAX4(e0, e1, e2, e3)
    M0 = fmaxf(M0, e0); M1 = fmaxf(M1, e1);
    M2 = fmaxf(M2, e2); M3 = fmaxf(M3, e3);
  }
  float S0 = 0.f, S1 = 0.f, S2 = 0.f, S3 = 0.f;
  for (int c = lo; c < hi; c += 64) {
    int j = c + lane;
    int sv = (j < hi) ? csr_src[j] : 0;
    float4 a4 = ((const float4*)asrc)[sv];
    bool valid = (j < hi);
    float e0 = valid ? lrelu(a4.x + ad4.x) : -1e30f;
    float e1 = valid ? lrelu(a4.y + ad4.y) : -1e30f;
    float e2 = valid ? lrelu(a4.z + ad4.z) : -1e30f;
    float e3 = valid ? lrelu(a4.w + ad4.w) : -1e30f;
    float w0 = expf(e0 - M0), w1 = expf(e1 - M1);
    float w2 = expf(e2 - M2), w3 = expf(e3 - M3);
    float s0 = w0, s1 = w1, s2 = w2, s3 = w3;
    BFLY_SUM4(s0, s1, s2, s3)
    S0 += s0; S1 += s1; S2 += s2; S3 += s3;
    sv_lds[wl][lane] = sv;
    *(float4*)&w_lds[wl][lane][0] = make_float4(w0, w1, w2, w3);
    int cnt = (hi - c < 64) ? (hi - c) : 64;
    for (int jj = 0; jj < cnt; jj++) {
      int i0 = sv_lds[wl][jj];
      float wA = w_lds[wl][jj][head];
      float2 h0 = *(const float2*)(h + (size_t)i0 * HC + lane * 2);
      ax += wA * h0.x; ay += wA * h0.y;
    }
  }
  float S = (head == 0) ? S0 : (head == 1) ? S1 : (head == 2) ? S2 : S3;
  float rden = 1.f / S;
  float2 b = *(const float2*)(bias + lane * 2);
  float vx = fmaxf(ax * rden + b.x, 0.f);
  float vy = fmaxf(ay * rden + b.y, 0.f);
  *(float2*)(out_h + (size_t)node * HC + lane * 2) = make_float2(vx, vy);
  if (do_pool) {
    int g = batch[node];
    unsigned* pp = pooled + g * HC + lane * 2;
    atomicMax(pp + 0, __float_as_uint(vx));
    atomicMax(pp + 1, __float_as_uint(vy));
  }
}

// final head: out[g] = (pooled[g] @ Wlin + blin) @ Wout + bout ; 1 block/graph
__global__ __launch_bounds__(256) void k_mlp(
    const float* __restrict__ pooled, const float* __restrict__ Wlin,
    const float* __restrict__ blin, const float* __restrict__ Wout,
    const float* __restrict__ bout, float* __restrict__ out) {
  __shared__ float p[HC];
  __shared__ float z[LIN];
  int g = blockIdx.x, tid = threadIdx.x;
  if (tid < HC) p[tid] = pooled[g * HC + tid];
  __syncthreads();
  float zv = blin[tid];
  for (int k = 0; k < HC; k++) zv += p[k] * Wlin[k * LIN + tid];
  z[tid] = zv;
  __syncthreads();
  if (tid < OUTC) {
    float o = bout[tid];
    for (int k = 0; k < LIN; k++) o += z[k] * Wout[k * OUTC + tid];
    out[g * OUTC + tid] = o;
  }
}

extern "C" void kernel_launch(void* const* d_in, const int* in_sizes, int n_in,
                              void* d_out, int out_size, void* d_ws, size_t ws_size,
                              hipStream_t stream) {
  const float* x     = (const float*)d_in[0];
  const int*   ei    = (const int*)d_in[1];
  const int*   batch = (const int*)d_in[2];
  const float* Wl[3] = {(const float*)d_in[3], (const float*)d_in[7], (const float*)d_in[11]};
  const float* As[3] = {(const float*)d_in[4], (const float*)d_in[8], (const float*)d_in[12]};
  const float* Ad[3] = {(const float*)d_in[5], (const float*)d_in[9], (const float*)d_in[13]};
  const float* Bi[3] = {(const float*)d_in[6], (const float*)d_in[10], (const float*)d_in[14]};
  const float* Wlin  = (const float*)d_in[15];
  const float* blin  = (const float*)d_in[16];
  const float* Wout  = (const float*)d_in[17];
  const float* bout  = (const float*)d_in[18];
  float* out = (float*)d_out;

  // workspace layout (float offsets), total ~14.21M floats = ~56.8 MB
  float* ws = (float*)d_ws;
  float*    h       = ws;                          // N*128
  float*    nodeB   = ws + 6400000;                // N*128
  float*    asrc    = ws + 12800000;               // N*4
  float*    adst    = ws + 13000000;               // N*4
  int*      deg     = (int*)(ws + 13200000);       // N
  int*      cnt     = (int*)(ws + 13250000);       // N (adjacent to deg)
  int*      row_off = (int*)(ws + 13300000);       // N+1
  int*      csr_src = (int*)(ws + 13350008);       // E_TOT
  unsigned* pooled  = (unsigned*)(ws + 14200008);  // 64*128

  const int* srcp = ei;
  const int* dstp = ei + E_EDGES;

  hipMemsetAsync(deg, 0, 2 * N_NODES * sizeof(int), stream);
  hipMemsetAsync(pooled, 0, NG * HC * sizeof(unsigned), stream);

  // CSR by dst — built once, reused by all 3 layers
  k_hist<<<(E_TOT + 255) / 256, 256, 0, stream>>>(dstp, deg);
  k_scan<<<1, 1024, 0, stream>>>(deg, row_off);
  k_scatter<<<(E_TOT + 255) / 256, 256, 0, stream>>>(srcp, dstp, row_off, cnt, csr_src);

  const float* lin_in = x;
  for (int L = 0; L < 3; L++) {
    k_gemm_alpha<<<(N_NODES + 127) / 128, 256, 0, stream>>>(
        lin_in, Wl[L], As[L], Ad[L], h, asrc, adst);
    k_aggr<<<(N_NODES * 64 + 255) / 256, 256, 0, stream>>>(
        row_off, csr_src, asrc, adst, h, Bi[L], batch,
        nodeB, pooled, (L == 2) ? 1 : 0);
    lin_in = nodeB;
  }
  k_mlp<<<NG, 256, 0, stream>>>((const float*)pooled, Wlin, blin, Wout, bout, out);
}

// Round 6
// 651.993 us; speedup vs baseline: 1.4272x; 1.4272x over previous
//
#include <hip/hip_runtime.h>
#include <math.h>

#define N_NODES 50000
#define E_EDGES 800000
#define E_TOT   850000   // E + N self loops
#define HC 128
#define NHEAD 4
#define LIN 256
#define OUTC 10
#define NG 64
#define NEG_SLOPE 0.2f

__device__ __forceinline__ float lrelu(float v) { return v > 0.f ? v : NEG_SLOPE * v; }

// ---------------------------------------------------------------------------
// GEMM + attention logits: h = x@W (N x128 @ 128x128); alpha_{src,dst}[n,h].
// 4 rows x 16 cols per thread; cols interleaved (c = t*4 + 32u) so each
// ds_read_b128 hits all 32 banks conflict-free. x loads broadcast across the
// 8 threads sharing a row (one 16B request per 8 lanes) -> x traffic ~1x.
// ---------------------------------------------------------------------------
__global__ __launch_bounds__(256, 2) void k_gemm_alpha(
    const float* __restrict__ x, const float* __restrict__ W,
    const float* __restrict__ a_s, const float* __restrict__ a_d,
    float* __restrict__ h, float* __restrict__ asrc, float* __restrict__ adst) {
  __shared__ float Ws[HC * HC];  // 64 KB
  int tid = threadIdx.x;
  {
    const float4* Wg = (const float4*)W;
    float4* Wv = (float4*)Ws;
#pragma unroll
    for (int i = 0; i < 16; i++) Wv[tid + i * 256] = Wg[tid + i * 256];
  }
  __syncthreads();
  int rl = tid >> 3, t = tid & 7;
  int base = blockIdx.x * 128;
  int row[4];
  const float4* xr[4];
#pragma unroll
  for (int r = 0; r < 4; r++) {
    row[r] = base + rl + 32 * r;
    int rc = row[r] < N_NODES ? row[r] : N_NODES - 1;  // clamp, store-guarded
    xr[r] = (const float4*)(x + (size_t)rc * HC);
  }
  float acc[4][16];
#pragma unroll
  for (int r = 0; r < 4; r++)
#pragma unroll
    for (int j = 0; j < 16; j++) acc[r][j] = 0.f;

  for (int k4 = 0; k4 < 32; k4++) {
    float4 xa = xr[0][k4], xb = xr[1][k4], xc = xr[2][k4], xd = xr[3][k4];
#pragma unroll
    for (int kk = 0; kk < 4; kk++) {
      const float* wb = Ws + (k4 * 4 + kk) * HC + t * 4;
      float4 w0 = *(const float4*)(wb);
      float4 w1 = *(const float4*)(wb + 32);
      float4 w2 = *(const float4*)(wb + 64);
      float4 w3 = *(const float4*)(wb + 96);
      float xs[4];
      xs[0] = (kk == 0) ? xa.x : (kk == 1) ? xa.y : (kk == 2) ? xa.z : xa.w;
      xs[1] = (kk == 0) ? xb.x : (kk == 1) ? xb.y : (kk == 2) ? xb.z : xb.w;
      xs[2] = (kk == 0) ? xc.x : (kk == 1) ? xc.y : (kk == 2) ? xc.z : xc.w;
      xs[3] = (kk == 0) ? xd.x : (kk == 1) ? xd.y : (kk == 2) ? xd.z : xd.w;
#pragma unroll
      for (int r = 0; r < 4; r++) {
        float xv = xs[r];
        acc[r][0] += xv * w0.x;  acc[r][1] += xv * w0.y;
        acc[r][2] += xv * w0.z;  acc[r][3] += xv * w0.w;
        acc[r][4] += xv * w1.x;  acc[r][5] += xv * w1.y;
        acc[r][6] += xv * w1.z;  acc[r][7] += xv * w1.w;
        acc[r][8] += xv * w2.x;  acc[r][9] += xv * w2.y;
        acc[r][10] += xv * w2.z; acc[r][11] += xv * w2.w;
        acc[r][12] += xv * w3.x; acc[r][13] += xv * w3.y;
        acc[r][14] += xv * w3.z; acc[r][15] += xv * w3.w;
      }
    }
  }

#pragma unroll
  for (int r = 0; r < 4; r++) {
    // col c = t*4 + 32u + j  ->  head = u, channel = t*4 + j
    float ps[4], pd[4];
#pragma unroll
    for (int u = 0; u < 4; u++) {
      float s = 0.f, d = 0.f;
#pragma unroll
      for (int j = 0; j < 4; j++) {
        float av = acc[r][u * 4 + j];
        s += av * a_s[u * 32 + t * 4 + j];
        d += av * a_d[u * 32 + t * 4 + j];
      }
      s += __shfl_xor(s, 1); s += __shfl_xor(s, 2); s += __shfl_xor(s, 4);
      d += __shfl_xor(d, 1); d += __shfl_xor(d, 2); d += __shfl_xor(d, 4);
      ps[u] = s; pd[u] = d;
    }
    if (row[r] < N_NODES) {
      float* hr = h + (size_t)row[r] * HC;
#pragma unroll
      for (int u = 0; u < 4; u++)
        *(float4*)(hr + t * 4 + 32 * u) = make_float4(
            acc[r][u * 4 + 0], acc[r][u * 4 + 1], acc[r][u * 4 + 2], acc[r][u * 4 + 3]);
      if (t < 4) {
        float vs = (t == 0) ? ps[0] : (t == 1) ? ps[1] : (t == 2) ? ps[2] : ps[3];
        float vd = (t == 0) ? pd[0] : (t == 1) ? pd[1] : (t == 2) ? pd[2] : pd[3];
        asrc[row[r] * NHEAD + t] = vs;
        adst[row[r] * NHEAD + t] = vd;
      }
    }
  }
}

// ---------------------------------------------------------------------------
// CSR build: histogram -> exclusive scan -> scatter (int atomics only)
// ---------------------------------------------------------------------------
__global__ __launch_bounds__(256) void k_hist(
    const int* __restrict__ dst, int* __restrict__ deg) {
  int e = blockIdx.x * 256 + threadIdx.x;
  if (e >= E_TOT) return;
  int d = (e < E_EDGES) ? dst[e] : e - E_EDGES;
  atomicAdd(&deg[d], 1);
}

__global__ __launch_bounds__(1024) void k_scan(
    const int* __restrict__ deg, int* __restrict__ row_off) {
  __shared__ int ps[1024];
  int tid = threadIdx.x;
  const int CH = (N_NODES + 1023) / 1024;  // 49
  int base = tid * CH;
  int sum = 0;
  for (int i = 0; i < CH; i++) {
    int idx = base + i;
    if (idx < N_NODES) sum += deg[idx];
  }
  ps[tid] = sum;
  __syncthreads();
  for (int off = 1; off < 1024; off <<= 1) {
    int v = (tid >= off) ? ps[tid - off] : 0;
    __syncthreads();
    ps[tid] += v;
    __syncthreads();
  }
  int run = (tid ? ps[tid - 1] : 0);
  for (int i = 0; i < CH; i++) {
    int idx = base + i;
    if (idx < N_NODES) { row_off[idx] = run; run += deg[idx]; }
  }
  if (tid == 1023) row_off[N_NODES] = run;
}

__global__ __launch_bounds__(256) void k_scatter(
    const int* __restrict__ src, const int* __restrict__ dst,
    const int* __restrict__ row_off, int* __restrict__ cnt,
    int* __restrict__ csr_src) {
  int e = blockIdx.x * 256 + threadIdx.x;
  if (e >= E_TOT) return;
  int s, d;
  if (e < E_EDGES) { s = src[e]; d = dst[e]; } else { s = d = e - E_EDGES; }
  int pos = row_off[d] + atomicAdd(&cnt[d], 1);
  csr_src[pos] = s;
}

#define BFLY_MAX4(m0, m1, m2, m3)                         \
  _Pragma("unroll") for (int off = 1; off < 64; off <<= 1) { \
    m0 = fmaxf(m0, __shfl_xor(m0, off));                  \
    m1 = fmaxf(m1, __shfl_xor(m1, off));                  \
    m2 = fmaxf(m2, __shfl_xor(m2, off));                  \
    m3 = fmaxf(m3, __shfl_xor(m3, off));                  \
  }
#define BFLY_SUM4(s0, s1, s2, s3)                         \
  _Pragma("unroll") for (int off = 1; off < 64; off <<= 1) { \
    s0 += __shfl_xor(s0, off);                            \
    s1 += __shfl_xor(s1, off);                            \
    s2 += __shfl_xor(s2, off);                            \
    s3 += __shfl_xor(s3, off);                            \
  }

// ---------------------------------------------------------------------------
// Fused softmax + aggregation (R4 structure — known good at 159 us).
// One wave per dst node; lane owns 2 feats; head = lane/16.
// Stage 1: lane j loads edge j's index + asrc once, stats via butterfly
//          shuffles, per-edge weights parked in LDS.
// Stage 2: plain unroll x8 (was x4): 8 independent coalesced 512B h-gathers
//          in flight; state lives only within an iteration -> no spill.
// Fused bias+relu+(final) max-pool epilogue.
// ---------------------------------------------------------------------------
__global__ __launch_bounds__(256) void k_aggr(
    const int* __restrict__ row_off, const int* __restrict__ csr_src,
    const float* __restrict__ asrc, const float* __restrict__ adst,
    const float* __restrict__ h, const float* __restrict__ bias,
    const int* __restrict__ batch, float* __restrict__ out_h,
    unsigned* __restrict__ pooled, int do_pool) {
  __shared__ int   sv_lds[4][64];
  __shared__ float w_lds[4][64][4];
  int gid = blockIdx.x * 256 + threadIdx.x;
  int node = gid >> 6, lane = gid & 63, wl = threadIdx.x >> 6;
  if (node >= N_NODES) return;
  int head = lane >> 4;
  int lo = row_off[node], hi = row_off[node + 1];
  int deg = hi - lo;
  float4 ad4 = ((const float4*)adst)[node];  // broadcast
  float ax = 0.f, ay = 0.f;
  float S;

  if (deg <= 64) {
    int j = lo + lane;
    int sv = (j < hi) ? csr_src[j] : 0;
    float4 a4 = ((const float4*)asrc)[sv];
    bool valid = (j < hi);
    float e0 = valid ? lrelu(a4.x + ad4.x) : -1e30f;
    float e1 = valid ? lrelu(a4.y + ad4.y) : -1e30f;
    float e2 = valid ? lrelu(a4.z + ad4.z) : -1e30f;
    float e3 = valid ? lrelu(a4.w + ad4.w) : -1e30f;
    float m0 = e0, m1 = e1, m2 = e2, m3 = e3;
    BFLY_MAX4(m0, m1, m2, m3)
    float w0 = expf(e0 - m0), w1 = expf(e1 - m1);
    float w2 = expf(e2 - m2), w3 = expf(e3 - m3);  // invalid lanes -> 0
    float s0 = w0, s1 = w1, s2 = w2, s3 = w3;
    BFLY_SUM4(s0, s1, s2, s3)
    sv_lds[wl][lane] = sv;
    *(float4*)&w_lds[wl][lane][0] = make_float4(w0, w1, w2, w3);
    S = (head == 0) ? s0 : (head == 1) ? s1 : (head == 2) ? s2 : s3;
    int jj = 0;
    for (; jj + 8 <= deg; jj += 8) {
      int i0 = sv_lds[wl][jj + 0], i1 = sv_lds[wl][jj + 1];
      int i2 = sv_lds[wl][jj + 2], i3 = sv_lds[wl][jj + 3];
      int i4 = sv_lds[wl][jj + 4], i5 = sv_lds[wl][jj + 5];
      int i6 = sv_lds[wl][jj + 6], i7 = sv_lds[wl][jj + 7];
      float wA = w_lds[wl][jj + 0][head], wB = w_lds[wl][jj + 1][head];
      float wC = w_lds[wl][jj + 2][head], wD = w_lds[wl][jj + 3][head];
      float wE = w_lds[wl][jj + 4][head], wF = w_lds[wl][jj + 5][head];
      float wG = w_lds[wl][jj + 6][head], wH = w_lds[wl][jj + 7][head];
      float2 h0 = *(const float2*)(h + (size_t)i0 * HC + lane * 2);
      float2 h1 = *(const float2*)(h + (size_t)i1 * HC + lane * 2);
      float2 h2 = *(const float2*)(h + (size_t)i2 * HC + lane * 2);
      float2 h3 = *(const float2*)(h + (size_t)i3 * HC + lane * 2);
      float2 h4 = *(const float2*)(h + (size_t)i4 * HC + lane * 2);
      float2 h5 = *(const float2*)(h + (size_t)i5 * HC + lane * 2);
      float2 h6 = *(const float2*)(h + (size_t)i6 * HC + lane * 2);
      float2 h7 = *(const float2*)(h + (size_t)i7 * HC + lane * 2);
      ax += wA * h0.x; ay += wA * h0.y;
      ax += wB * h1.x; ay += wB * h1.y;
      ax += wC * h2.x; ay += wC * h2.y;
      ax += wD * h3.x; ay += wD * h3.y;
      ax += wE * h4.x; ay += wE * h4.y;
      ax += wF * h5.x; ay += wF * h5.y;
      ax += wG * h6.x; ay += wG * h6.y;
      ax += wH * h7.x; ay += wH * h7.y;
    }
    for (; jj + 4 <= deg; jj += 4) {
      int i0 = sv_lds[wl][jj + 0], i1 = sv_lds[wl][jj + 1];
      int i2 = sv_lds[wl][jj + 2], i3 = sv_lds[wl][jj + 3];
      float wA = w_lds[wl][jj + 0][head], wB = w_lds[wl][jj + 1][head];
      float wC = w_lds[wl][jj + 2][head], wD = w_lds[wl][jj + 3][head];
      float2 h0 = *(const float2*)(h + (size_t)i0 * HC + lane * 2);
      float2 h1 = *(const float2*)(h + (size_t)i1 * HC + lane * 2);
      float2 h2 = *(const float2*)(h + (size_t)i2 * HC + lane * 2);
      float2 h3 = *(const float2*)(h + (size_t)i3 * HC + lane * 2);
      ax += wA * h0.x; ay += wA * h0.y;
      ax += wB * h1.x; ay += wB * h1.y;
      ax += wC * h2.x; ay += wC * h2.y;
      ax += wD * h3.x; ay += wD * h3.y;
    }
    for (; jj < deg; jj++) {
      int i0 = sv_lds[wl][jj];
      float wA = w_lds[wl][jj][head];
      float2 h0 = *(const float2*)(h + (size_t)i0 * HC + lane * 2);
      ax += wA * h0.x; ay += wA * h0.y;
    }
  } else {
    // rare generic path (deg > 64): chunked two-pass
    float M0 = -1e30f, M1 = -1e30f, M2 = -1e30f, M3 = -1e30f;
    for (int c = lo; c < hi; c += 64) {
      int j = c + lane;
      int sv = (j < hi) ? csr_src[j] : 0;
      float4 a4 = ((const float4*)asrc)[sv];
      bool valid = (j < hi);
      float e0 = valid ? lrelu(a4.x + ad4.x) : -1e30f;
      float e1 = valid ? lrelu(a4.y + ad4.y) : -1e30f;
      float e2 = valid ? lrelu(a4.z + ad4.z) : -1e30f;
      float e3 = valid ? lrelu(a4.w + ad4.w) : -1e30f;
      BFLY_MAX4(e0, e1, e2, e3)
      M0 = fmaxf(M0, e0); M1 = fmaxf(M1, e1);
      M2 = fmaxf(M2, e2); M3 = fmaxf(M3, e3);
    }
    float S0 = 0.f, S1 = 0.f, S2 = 0.f, S3 = 0.f;
    for (int c = lo; c < hi; c += 64) {
      int j = c + lane;
      int sv = (j < hi) ? csr_src[j] : 0;
      float4 a4 = ((const float4*)asrc)[sv];
      bool valid = (j < hi);
      float e0 = valid ? lrelu(a4.x + ad4.x) : -1e30f;
      float e1 = valid ? lrelu(a4.y + ad4.y) : -1e30f;
      float e2 = valid ? lrelu(a4.z + ad4.z) : -1e30f;
      float e3 = valid ? lrelu(a4.w + ad4.w) : -1e30f;
      float w0 = expf(e0 - M0), w1 = expf(e1 - M1);
      float w2 = expf(e2 - M2), w3 = expf(e3 - M3);
      float s0 = w0, s1 = w1, s2 = w2, s3 = w3;
      BFLY_SUM4(s0, s1, s2, s3)
      S0 += s0; S1 += s1; S2 += s2; S3 += s3;
      sv_lds[wl][lane] = sv;
      *(float4*)&w_lds[wl][lane][0] = make_float4(w0, w1, w2, w3);
      int cnt = (hi - c < 64) ? (hi - c) : 64;
      int jj = 0;
      for (; jj + 4 <= cnt; jj += 4) {
        int i0 = sv_lds[wl][jj + 0], i1 = sv_lds[wl][jj + 1];
        int i2 = sv_lds[wl][jj + 2], i3 = sv_lds[wl][jj + 3];
        float wA = w_lds[wl][jj + 0][head], wB = w_lds[wl][jj + 1][head];
        float wC = w_lds[wl][jj + 2][head], wD = w_lds[wl][jj + 3][head];
        float2 h0 = *(const float2*)(h + (size_t)i0 * HC + lane * 2);
        float2 h1 = *(const float2*)(h + (size_t)i1 * HC + lane * 2);
        float2 h2 = *(const float2*)(h + (size_t)i2 * HC + lane * 2);
        float2 h3 = *(const float2*)(h + (size_t)i3 * HC + lane * 2);
        ax += wA * h0.x; ay += wA * h0.y;
        ax += wB * h1.x; ay += wB * h1.y;
        ax += wC * h2.x; ay += wC * h2.y;
        ax += wD * h3.x; ay += wD * h3.y;
      }
      for (; jj < cnt; jj++) {
        int i0 = sv_lds[wl][jj];
        float wA = w_lds[wl][jj][head];
        float2 h0 = *(const float2*)(h + (size_t)i0 * HC + lane * 2);
        ax += wA * h0.x; ay += wA * h0.y;
      }
    }
    S = (head == 0) ? S0 : (head == 1) ? S1 : (head == 2) ? S2 : S3;
  }

  float rden = 1.f / S;
  float2 b = *(const float2*)(bias + lane * 2);
  float vx = fmaxf(ax * rden + b.x, 0.f);
  float vy = fmaxf(ay * rden + b.y, 0.f);
  *(float2*)(out_h + (size_t)node * HC + lane * 2) = make_float2(vx, vy);
  if (do_pool) {
    int g = batch[node];
    unsigned* pp = pooled + g * HC + lane * 2;
    // post-relu values >= 0: bit compare == float compare; init 0 matches the
    // reference's where(isfinite, pooled, 0) empty-graph guard.
    atomicMax(pp + 0, __float_as_uint(vx));
    atomicMax(pp + 1, __float_as_uint(vy));
  }
}

// final head: out[g] = (pooled[g] @ Wlin + blin) @ Wout + bout ; 1 block/graph
__global__ __launch_bounds__(256) void k_mlp(
    const float* __restrict__ pooled, const float* __restrict__ Wlin,
    const float* __restrict__ blin, const float* __restrict__ Wout,
    const float* __restrict__ bout, float* __restrict__ out) {
  __shared__ float p[HC];
  __shared__ float z[LIN];
  int g = blockIdx.x, tid = threadIdx.x;
  if (tid < HC) p[tid] = pooled[g * HC + tid];
  __syncthreads();
  float zv = blin[tid];
  for (int k = 0; k < HC; k++) zv += p[k] * Wlin[k * LIN + tid];
  z[tid] = zv;
  __syncthreads();
  if (tid < OUTC) {
    float o = bout[tid];
    for (int k = 0; k < LIN; k++) o += z[k] * Wout[k * OUTC + tid];
    out[g * OUTC + tid] = o;
  }
}

extern "C" void kernel_launch(void* const* d_in, const int* in_sizes, int n_in,
                              void* d_out, int out_size, void* d_ws, size_t ws_size,
                              hipStream_t stream) {
  const float* x     = (const float*)d_in[0];
  const int*   ei    = (const int*)d_in[1];
  const int*   batch = (const int*)d_in[2];
  const float* Wl[3] = {(const float*)d_in[3], (const float*)d_in[7], (const float*)d_in[11]};
  const float* As[3] = {(const float*)d_in[4], (const float*)d_in[8], (const float*)d_in[12]};
  const float* Ad[3] = {(const float*)d_in[5], (const float*)d_in[9], (const float*)d_in[13]};
  const float* Bi[3] = {(const float*)d_in[6], (const float*)d_in[10], (const float*)d_in[14]};
  const float* Wlin  = (const float*)d_in[15];
  const float* blin  = (const float*)d_in[16];
  const float* Wout  = (const float*)d_in[17];
  const float* bout  = (const float*)d_in[18];
  float* out = (float*)d_out;

  // workspace layout (float offsets), total ~14.21M floats = ~56.8 MB
  float* ws = (float*)d_ws;
  float*    h       = ws;                          // N*128
  float*    nodeB   = ws + 6400000;                // N*128
  float*    asrc    = ws + 12800000;               // N*4
  float*    adst    = ws + 13000000;               // N*4
  int*      deg     = (int*)(ws + 13200000);       // N
  int*      cnt     = (int*)(ws + 13250000);       // N (adjacent to deg)
  int*      row_off = (int*)(ws + 13300000);       // N+1
  int*      csr_src = (int*)(ws + 13350008);       // E_TOT
  unsigned* pooled  = (unsigned*)(ws + 14200008);  // 64*128

  const int* srcp = ei;
  const int* dstp = ei + E_EDGES;

  hipMemsetAsync(deg, 0, 2 * N_NODES * sizeof(int), stream);
  hipMemsetAsync(pooled, 0, NG * HC * sizeof(unsigned), stream);

  // CSR by dst — built once, reused by all 3 layers
  k_hist<<<(E_TOT + 255) / 256, 256, 0, stream>>>(dstp, deg);
  k_scan<<<1, 1024, 0, stream>>>(deg, row_off);
  k_scatter<<<(E_TOT + 255) / 256, 256, 0, stream>>>(srcp, dstp, row_off, cnt, csr_src);

  const float* lin_in = x;
  for (int L = 0; L < 3; L++) {
    k_gemm_alpha<<<(N_NODES + 127) / 128, 256, 0, stream>>>(
        lin_in, Wl[L], As[L], Ad[L], h, asrc, adst);
    k_aggr<<<(N_NODES * 64 + 255) / 256, 256, 0, stream>>>(
        row_off, csr_src, asrc, adst, h, Bi[L], batch,
        nodeB, pooled, (L == 2) ? 1 : 0);
    lin_in = nodeB;
  }
  k_mlp<<<NG, 256, 0, stream>>>((const float*)pooled, Wlin, blin, Wout, bout, out);
}